// Round 7
// baseline (96.909 us; speedup 1.0000x reference)
//
#include <hip/hip_runtime.h>
#include <hip/hip_bf16.h>

#define UNIT_NO 512
#define T_DIM 25
#define K_DIM 20
#define H_DIM 64
#define P_DIM 4096
#define F_DIM 10
#define BATCH 32
#define KTOT (K_DIM * F_DIM)   // 200
#define KPAD 224               // 7 MFMA k-tiles of 32 (pad zeroed)
#define LSTR 232               // LDS k-stride (elems): 464B = 29*16 -> 16B aligned rows, bank-uniform
#define FT_STR 16              // Ft per-(u,b) f-stride (padded 10->16 for aligned float4)

typedef short bf16x8 __attribute__((ext_vector_type(8)));
typedef float f32x4 __attribute__((ext_vector_type(4)));

__device__ inline unsigned short bf16b(float x) {
    __hip_bfloat16 h = __float2bfloat16(x);   // RNE
    return *(unsigned short*)&h;
}
__device__ inline unsigned int pack2(float lo, float hi) {
    return (unsigned int)bf16b(lo) | ((unsigned int)bf16b(hi) << 16);
}

// Kernel A: per-unit featurize for units [0, Ustar).
// Layout Ft[u][b][16] (f contiguous, padded) so pixel staging reads aligned vectors.
__global__ __launch_bounds__(320) void featurize_kernel(
    const float* __restrict__ S, const float* __restrict__ Wf,
    const float* __restrict__ bf, float* __restrict__ Ft)
{
    const int u = blockIdx.x;
    __shared__ float Ws[T_DIM * F_DIM];   // [t][f]
    __shared__ float Ss[BATCH * T_DIM];   // [b][t]
    const int tid = threadIdx.x;
    for (int i = tid; i < T_DIM * F_DIM; i += 320)
        Ws[i] = Wf[u * (T_DIM * F_DIM) + i];
    for (int i = tid; i < BATCH * T_DIM; i += 320) {
        int b = i / T_DIM;
        int t = i - b * T_DIM;
        Ss[i] = S[b * (UNIT_NO * T_DIM) + u * T_DIM + t];
    }
    __syncthreads();
    const int b = tid / F_DIM;    // 0..31
    const int f = tid - b * F_DIM;
    float acc = 0.f;
#pragma unroll
    for (int t = 0; t < T_DIM; ++t)
        acc = fmaf(Ss[b * T_DIM + t], Ws[t * F_DIM + f], acc);
    Ft[(u * BATCH + b) * FT_STR + f] = acc + bf[u * F_DIM + f];
}

// Kernel B: one block (256 thr, 4 waves) per pixel, bf16 MFMA.
//   C[b=32][h=64] = G[b][k=200] * W1[k][h], fp32 accumulate.
//   LDS: Gb[b][k] bf16 (A operand, k contiguous), Wt[h][k] bf16 (B operand,
//   k contiguous — transposed+converted during staging).
//   Wave wv owns htile=wv (16 h), both btiles. 7 k-tiles of 32 (k>=200 zero).
//   Fragment rule (gfx950 16x16x32): lane l elem j -> k = 8*(l/16)+j, m/n = l%16;
//   D: col=l%16, row=(l/16)*4+reg (m89-verified).
__global__ __launch_bounds__(256, 4) void pixel_kernel(
    const float* __restrict__ Ft, const int* __restrict__ pix_units,
    const float* __restrict__ W1, const float* __restrict__ b1,
    const float* __restrict__ a, const float* __restrict__ Wo,
    const float* __restrict__ bo, float* __restrict__ out,
    const float* __restrict__ S, const float* __restrict__ Wf,
    const float* __restrict__ bf, int Ustar)
{
    const int p = blockIdx.x;
    const int tid = threadIdx.x;
    const int lane = tid & 63;
    const int wv = tid >> 6;

    __shared__ unsigned short Wt[H_DIM][LSTR];   // 29.7 KB
    __shared__ unsigned short Gb[BATCH][LSTR];   // 14.8 KB
    __shared__ float red[4][BATCH];
    __shared__ int us[K_DIM];

    if (tid < K_DIM) us[tid] = pix_units[p * K_DIM + tid];

    // Zero the k-pad [KTOT, KPAD) of both operands.
    for (int i = tid; i < (H_DIM + BATCH) * (KPAD - KTOT); i += 256) {
        int row = i / (KPAD - KTOT);
        int c   = i - row * (KPAD - KTOT);
        if (row < H_DIM) Wt[row][KTOT + c] = 0;
        else             Gb[row - H_DIM][KTOT + c] = 0;
    }
    __syncthreads();   // us[] visible

    // --- Stage W1 transposed+bf16: Wt[h][k] = bf16(W1[k][h]) ---
    // Thread t: h = t&63, k-quad base kg = (t>>6)*4; per iter 4 per-j-coalesced
    // dword loads (lanes sweep h), pack to 2 dwords, one 8B LDS write.
    {
        const float* __restrict__ w1p = W1 + (size_t)p * (KTOT * H_DIM);
        const int h  = tid & 63;
        const int kg = (tid >> 6) << 2;
#pragma unroll
        for (int i = 0; i < 13; ++i) {
            const int k0 = kg + 16 * i;
            if (k0 < KTOT) {
                float f0 = w1p[(k0 + 0) * H_DIM + h];
                float f1 = w1p[(k0 + 1) * H_DIM + h];
                float f2 = w1p[(k0 + 2) * H_DIM + h];
                float f3 = w1p[(k0 + 3) * H_DIM + h];
                uint2 v = make_uint2(pack2(f0, f1), pack2(f2, f3));
                *(uint2*)(&Wt[h][k0]) = v;   // (h*464 + 2*k0) % 8 == 0
            }
        }
    }

    // --- Stage gathered features bf16: Gb[b][j*10+f] = bf16(F[us[j]][b][f]) ---
    for (int task = tid; task < K_DIM * BATCH; task += 256) {
        const int j = task >> 5;
        const int b = task & 31;
        const int u = us[j];
        float g[10];
        if (u < Ustar) {
            const float* __restrict__ src = Ft + ((size_t)(u * BATCH + b) * FT_STR);
            float4 a0 = *(const float4*)(src);
            float4 a1 = *(const float4*)(src + 4);
            float2 a2 = *(const float2*)(src + 8);
            g[0] = a0.x; g[1] = a0.y; g[2] = a0.z; g[3] = a0.w;
            g[4] = a1.x; g[5] = a1.y; g[6] = a1.z; g[7] = a1.w;
            g[8] = a2.x; g[9] = a2.y;
        } else {
            const float* __restrict__ sp = S + b * (UNIT_NO * T_DIM) + u * T_DIM;
            const float* __restrict__ wp = Wf + u * (T_DIM * F_DIM);
#pragma unroll
            for (int f = 0; f < F_DIM; ++f) {
                float acc = bf[u * F_DIM + f];
#pragma unroll
                for (int t = 0; t < T_DIM; ++t)
                    acc = fmaf(sp[t], wp[t * F_DIM + f], acc);
                g[f] = acc;
            }
        }
        unsigned int* dst = (unsigned int*)(&Gb[b][j * F_DIM]);  // byte off %4==0
        dst[0] = pack2(g[0], g[1]);
        dst[1] = pack2(g[2], g[3]);
        dst[2] = pack2(g[4], g[5]);
        dst[3] = pack2(g[6], g[7]);
        dst[4] = pack2(g[8], g[9]);
    }
    __syncthreads();

    // --- MFMA main loop: wave wv -> htile wv; btiles 0,1; 7 k-tiles ---
    const int l16 = lane & 15;
    const int l4  = lane >> 4;
    f32x4 acc0 = {0.f, 0.f, 0.f, 0.f};
    f32x4 acc1 = {0.f, 0.f, 0.f, 0.f};
    const unsigned short* __restrict__ Arow0 = &Gb[l16][8 * l4];
    const unsigned short* __restrict__ Arow1 = &Gb[16 + l16][8 * l4];
    const unsigned short* __restrict__ Brow  = &Wt[(wv << 4) + l16][8 * l4];
#pragma unroll
    for (int kt = 0; kt < KPAD / 32; ++kt) {
        bf16x8 fa0 = *(const bf16x8*)(Arow0 + kt * 32);
        bf16x8 fa1 = *(const bf16x8*)(Arow1 + kt * 32);
        bf16x8 fb  = *(const bf16x8*)(Brow  + kt * 32);
        acc0 = __builtin_amdgcn_mfma_f32_16x16x32_bf16(fa0, fb, acc0, 0, 0, 0);
        acc1 = __builtin_amdgcn_mfma_f32_16x16x32_bf16(fa1, fb, acc1, 0, 0, 0);
    }

    // --- Epilogue: bias + PReLU + Wo, reduce over h ---
    const int h = (wv << 4) + l16;
    const float b1v = b1[p * H_DIM + h];
    const float wov = Wo[p * H_DIM + h];
    const float av  = a[p];
    float s0[4], s1[4];
#pragma unroll
    for (int r = 0; r < 4; ++r) {
        float v0 = acc0[r] + b1v; v0 = (v0 >= 0.f) ? v0 : av * v0;
        float v1 = acc1[r] + b1v; v1 = (v1 >= 0.f) ? v1 : av * v1;
        s0[r] = v0 * wov;
        s1[r] = v1 * wov;
    }
    // sum over this wave's 16 h (lane bits 0..3)
#pragma unroll
    for (int off = 1; off < 16; off <<= 1)
#pragma unroll
        for (int r = 0; r < 4; ++r) {
            s0[r] += __shfl_xor(s0[r], off);
            s1[r] += __shfl_xor(s1[r], off);
        }
    if (l16 == 0) {
#pragma unroll
        for (int r = 0; r < 4; ++r) {
            red[wv][(l4 << 2) + r]      = s0[r];   // b = l4*4+r
            red[wv][16 + (l4 << 2) + r] = s1[r];   // b = 16+l4*4+r
        }
    }
    __syncthreads();
    if (tid < BATCH) {
        float v = red[0][tid] + red[1][tid] + red[2][tid] + red[3][tid] + bo[p];
        out[(size_t)tid * P_DIM + p] = v;
    }
}

extern "C" void kernel_launch(void* const* d_in, const int* in_sizes, int n_in,
                              void* d_out, int out_size, void* d_ws, size_t ws_size,
                              hipStream_t stream) {
    const float* S         = (const float*)d_in[0];
    const int*   pix_units = (const int*)d_in[1];
    const float* Wf        = (const float*)d_in[2];
    const float* bf        = (const float*)d_in[3];
    const float* W1        = (const float*)d_in[4];
    const float* b1        = (const float*)d_in[5];
    const float* a         = (const float*)d_in[6];
    const float* Wo        = (const float*)d_in[7];
    const float* bo        = (const float*)d_in[8];
    float* out = (float*)d_out;
    float* Ft  = (float*)d_ws;

    // Units whose padded [32][16] fp32 tile fits in ws_size; rest recomputed in-block.
    int Ustar = (int)(ws_size / (size_t)(BATCH * FT_STR * sizeof(float)));
    if (Ustar > UNIT_NO) Ustar = UNIT_NO;

    if (Ustar > 0)
        featurize_kernel<<<Ustar, 320, 0, stream>>>(S, Wf, bf, Ft);
    pixel_kernel<<<P_DIM, 256, 0, stream>>>(Ft, pix_units, W1, b1, a, Wo, bo, out,
                                            S, Wf, bf, Ustar);
}

// Round 8
// 66.251 us; speedup vs baseline: 1.4628x; 1.4628x over previous
//
#include <hip/hip_runtime.h>
#include <hip/hip_bf16.h>

#define UNIT_NO 512
#define T_DIM 25
#define K_DIM 20
#define H_DIM 64
#define P_DIM 4096
#define F_DIM 10
#define BATCH 32
#define KTOT (K_DIM * F_DIM)   // 200
#define KPAD 224               // 7 MFMA k-tiles of 32 (tail zeroed)
#define LSTR 232               // LDS row stride (halfwords): 464B = 29*16 -> odd quad stride, conflict-free b128
#define FT_STR 16              // Ft per-(u,b) f-stride (padded 10->16)

typedef short bf16x8 __attribute__((ext_vector_type(8)));
typedef float f32x4 __attribute__((ext_vector_type(4)));

__device__ inline unsigned short bf16b(float x) {
    __hip_bfloat16 h = __float2bfloat16(x);   // RNE
    return *(unsigned short*)&h;
}
__device__ inline unsigned int pack2(float lo, float hi) {
    return (unsigned int)bf16b(lo) | ((unsigned int)bf16b(hi) << 16);
}

// Kernel A: per-unit featurize for units [0, Ustar). Ft[u][b][16], f contiguous.
__global__ __launch_bounds__(320) void featurize_kernel(
    const float* __restrict__ S, const float* __restrict__ Wf,
    const float* __restrict__ bf, float* __restrict__ Ft)
{
    const int u = blockIdx.x;
    __shared__ float Ws[T_DIM * F_DIM];   // [t][f]
    __shared__ float Ss[BATCH * T_DIM];   // [b][t]
    const int tid = threadIdx.x;
    for (int i = tid; i < T_DIM * F_DIM; i += 320)
        Ws[i] = Wf[u * (T_DIM * F_DIM) + i];
    for (int i = tid; i < BATCH * T_DIM; i += 320) {
        int b = i / T_DIM;
        int t = i - b * T_DIM;
        Ss[i] = S[b * (UNIT_NO * T_DIM) + u * T_DIM + t];
    }
    __syncthreads();
    const int b = tid / F_DIM;    // 0..31
    const int f = tid - b * F_DIM;
    float acc = 0.f;
#pragma unroll
    for (int t = 0; t < T_DIM; ++t)
        acc = fmaf(Ss[b * T_DIM + t], Ws[t * F_DIM + f], acc);
    Ft[(u * BATCH + b) * FT_STR + f] = acc + bf[u * F_DIM + f];
}

// Kernel B: one block (256 thr) per pixel, bf16 MFMA (R7-verified fragment map).
// Staging rebuilt for ILP: branch-free bulk loads -> pack -> conflict-free
// ds_write_b128 transpose; single barrier before the MFMA phase.
__global__ __launch_bounds__(256, 3) void pixel_kernel(
    const float* __restrict__ Ft, const int* __restrict__ pix_units,
    const float* __restrict__ W1, const float* __restrict__ b1,
    const float* __restrict__ a, const float* __restrict__ Wo,
    const float* __restrict__ bo, float* __restrict__ out,
    const float* __restrict__ S, const float* __restrict__ Wf,
    const float* __restrict__ bf, int Ustar)
{
    const int p = blockIdx.x;
    const int tid = threadIdx.x;
    const int lane = tid & 63;     // = h for staging
    const int wv = tid >> 6;

    __shared__ unsigned short Wt[H_DIM][LSTR];   // 29.0 KB  (Wt[h][k])
    __shared__ unsigned short Gb[BATCH][LSTR];   // 14.5 KB  (Gb[b][k])
    __shared__ float red[4][BATCH];

    const float* __restrict__ w1p = W1 + (size_t)p * (KTOT * H_DIM);

    // ---- 1) us for this thread's Gb tasks (direct from global, L2-hot) ----
    int task_u[3];
#pragma unroll
    for (int it = 0; it < 3; ++it) {
        int task = tid + it * 256;
        if (task < K_DIM * BATCH)
            task_u[it] = pix_units[p * K_DIM + (task >> 5)];
    }

    // ---- 2) W1 bulk loads: wave wv owns k-octets wv*6..wv*6+5 (+24 for wv0) ----
    // Per load instruction: 64 lanes sweep h -> 256B contiguous. All loads
    // independent, statically indexed -> stay in registers, deep in flight.
    float f[6][8];
#pragma unroll
    for (int m = 0; m < 6; ++m) {
        const int k0 = (wv * 6 + m) << 3;
#pragma unroll
        for (int j = 0; j < 8; ++j)
            f[m][j] = w1p[(k0 + j) * H_DIM + lane];
    }
    float fx[8];
    if (wv == 0) {
#pragma unroll
        for (int j = 0; j < 8; ++j)
            fx[j] = w1p[(192 + j) * H_DIM + lane];
    }

    // ---- 3) Gb gather loads (dep only on task_u) ----
    float g[3][10];
#pragma unroll
    for (int it = 0; it < 3; ++it) {
        int task = tid + it * 256;
        if (task < K_DIM * BATCH) {
            const int b = task & 31;
            const int u = task_u[it];
            if (u < Ustar) {
                const float* __restrict__ src = Ft + ((size_t)(u * BATCH + b) * FT_STR);
                float4 a0 = *(const float4*)(src);
                float4 a1 = *(const float4*)(src + 4);
                float2 a2 = *(const float2*)(src + 8);
                g[it][0] = a0.x; g[it][1] = a0.y; g[it][2] = a0.z; g[it][3] = a0.w;
                g[it][4] = a1.x; g[it][5] = a1.y; g[it][6] = a1.z; g[it][7] = a1.w;
                g[it][8] = a2.x; g[it][9] = a2.y;
            } else {
                const float* __restrict__ sp = S + b * (UNIT_NO * T_DIM) + u * T_DIM;
                const float* __restrict__ wp = Wf + u * (T_DIM * F_DIM);
#pragma unroll
                for (int ff = 0; ff < F_DIM; ++ff) {
                    float acc = bf[u * F_DIM + ff];
#pragma unroll
                    for (int t = 0; t < T_DIM; ++t)
                        acc = fmaf(sp[t], wp[t * F_DIM + ff], acc);
                    g[it][ff] = acc;
                }
            }
        }
    }

    // ---- 4) Zero k-pad [200,224) of all 96 rows (uint2 = 4 halfwords) ----
    for (int i = tid; i < 96 * 6; i += 256) {
        const int row = i / 6;
        const int c   = i - row * 6;
        unsigned short* ptr = (row < H_DIM) ? &Wt[row][KTOT + (c << 2)]
                                            : &Gb[row - H_DIM][KTOT + (c << 2)];
        *(uint2*)ptr = make_uint2(0u, 0u);
    }

    // ---- 5) Pack + transposed Wt writes (ds_write_b128, conflict-free) ----
#pragma unroll
    for (int m = 0; m < 6; ++m) {
        const int oct = wv * 6 + m;
        uint4 v;
        v.x = pack2(f[m][0], f[m][1]);
        v.y = pack2(f[m][2], f[m][3]);
        v.z = pack2(f[m][4], f[m][5]);
        v.w = pack2(f[m][6], f[m][7]);
        *(uint4*)(&Wt[lane][oct << 3]) = v;   // byte off = lane*464 + oct*16
    }
    if (wv == 0) {
        uint4 v;
        v.x = pack2(fx[0], fx[1]);
        v.y = pack2(fx[2], fx[3]);
        v.z = pack2(fx[4], fx[5]);
        v.w = pack2(fx[6], fx[7]);
        *(uint4*)(&Wt[lane][192]) = v;
    }

    // ---- 6) Gb writes ----
#pragma unroll
    for (int it = 0; it < 3; ++it) {
        int task = tid + it * 256;
        if (task < K_DIM * BATCH) {
            const int j = task >> 5;
            const int b = task & 31;
            unsigned int* dst = (unsigned int*)(&Gb[b][j * F_DIM]);  // j*10 even
            dst[0] = pack2(g[it][0], g[it][1]);
            dst[1] = pack2(g[it][2], g[it][3]);
            dst[2] = pack2(g[it][4], g[it][5]);
            dst[3] = pack2(g[it][6], g[it][7]);
            dst[4] = pack2(g[it][8], g[it][9]);
        }
    }
    __syncthreads();

    // ---- 7) MFMA: wave wv -> htile wv; btiles 0,1; 7 k-tiles (R7-verified) ----
    const int l16 = lane & 15;
    const int l4  = lane >> 4;
    f32x4 acc0 = {0.f, 0.f, 0.f, 0.f};
    f32x4 acc1 = {0.f, 0.f, 0.f, 0.f};
    const unsigned short* __restrict__ Arow0 = &Gb[l16][8 * l4];
    const unsigned short* __restrict__ Arow1 = &Gb[16 + l16][8 * l4];
    const unsigned short* __restrict__ Brow  = &Wt[(wv << 4) + l16][8 * l4];
#pragma unroll
    for (int kt = 0; kt < KPAD / 32; ++kt) {
        bf16x8 fa0 = *(const bf16x8*)(Arow0 + kt * 32);
        bf16x8 fa1 = *(const bf16x8*)(Arow1 + kt * 32);
        bf16x8 fb  = *(const bf16x8*)(Brow  + kt * 32);
        acc0 = __builtin_amdgcn_mfma_f32_16x16x32_bf16(fa0, fb, acc0, 0, 0, 0);
        acc1 = __builtin_amdgcn_mfma_f32_16x16x32_bf16(fa1, fb, acc1, 0, 0, 0);
    }

    // ---- 8) Epilogue: bias + PReLU + Wo, reduce over h (R7-verified) ----
    const int h = (wv << 4) + l16;
    const float b1v = b1[p * H_DIM + h];
    const float wov = Wo[p * H_DIM + h];
    const float av  = a[p];
    float s0[4], s1[4];
#pragma unroll
    for (int r = 0; r < 4; ++r) {
        float v0 = acc0[r] + b1v; v0 = (v0 >= 0.f) ? v0 : av * v0;
        float v1 = acc1[r] + b1v; v1 = (v1 >= 0.f) ? v1 : av * v1;
        s0[r] = v0 * wov;
        s1[r] = v1 * wov;
    }
#pragma unroll
    for (int off = 1; off < 16; off <<= 1)
#pragma unroll
        for (int r = 0; r < 4; ++r) {
            s0[r] += __shfl_xor(s0[r], off);
            s1[r] += __shfl_xor(s1[r], off);
        }
    if (l16 == 0) {
#pragma unroll
        for (int r = 0; r < 4; ++r) {
            red[wv][(l4 << 2) + r]      = s0[r];   // b = l4*4+r
            red[wv][16 + (l4 << 2) + r] = s1[r];   // b = 16+l4*4+r
        }
    }
    __syncthreads();
    if (tid < BATCH) {
        float v = red[0][tid] + red[1][tid] + red[2][tid] + red[3][tid] + bo[p];
        out[(size_t)tid * P_DIM + p] = v;
    }
}

extern "C" void kernel_launch(void* const* d_in, const int* in_sizes, int n_in,
                              void* d_out, int out_size, void* d_ws, size_t ws_size,
                              hipStream_t stream) {
    const float* S         = (const float*)d_in[0];
    const int*   pix_units = (const int*)d_in[1];
    const float* Wf        = (const float*)d_in[2];
    const float* bf        = (const float*)d_in[3];
    const float* W1        = (const float*)d_in[4];
    const float* b1        = (const float*)d_in[5];
    const float* a         = (const float*)d_in[6];
    const float* Wo        = (const float*)d_in[7];
    const float* bo        = (const float*)d_in[8];
    float* out = (float*)d_out;
    float* Ft  = (float*)d_ws;

    // Units whose padded [32][16] fp32 tile fits in ws_size; rest recomputed in-block.
    int Ustar = (int)(ws_size / (size_t)(BATCH * FT_STR * sizeof(float)));
    if (Ustar > UNIT_NO) Ustar = UNIT_NO;

    if (Ustar > 0)
        featurize_kernel<<<Ustar, 320, 0, stream>>>(S, Wf, bf, Ft);
    pixel_kernel<<<P_DIM, 256, 0, stream>>>(Ft, pix_units, W1, b1, a, Wo, bo, out,
                                            S, Wf, bf, Ustar);
}